// Round 5
// baseline (316.814 us; speedup 1.0000x reference)
//
#include <hip/hip_runtime.h>
#include <cstdint>

// Problem constants
#define B_  4
#define T_  2048
#define D_  1024
#define H_  16
#define DH_ 64
#define R_  8
#define M_  (B_*T_)          // 8192
#define LORA_SCALE 4.0f

typedef __attribute__((ext_vector_type(8))) short    bf16x8;
typedef __attribute__((ext_vector_type(4))) short    bf16x4;
typedef __attribute__((ext_vector_type(4))) float    f32x4;
typedef __attribute__((ext_vector_type(4))) uint32_t u32x4;

__device__ inline uint16_t f2b(float f) {             // fp32 -> bf16 RNE
    uint32_t x = __float_as_uint(f);
    return (uint16_t)((x + 0x7fffu + ((x >> 16) & 1u)) >> 16);
}
__device__ inline float b2f(uint16_t u) { return __uint_as_float(((uint32_t)u) << 16); }

// packed f32x2 -> bf16x2 (no builtin on gfx950; pure VOP3 asm, schedulable)
__device__ __forceinline__ uint32_t cvtpk(float lo, float hi) {
    uint32_t r;
    asm("v_cvt_pk_bf16_f32 %0, %1, %2" : "=v"(r) : "v"(lo), "v"(hi));
    return r;
}
__device__ __forceinline__ float max3f(float a, float b, float c) {
    float r;
    asm("v_max3_f32 %0, %1, %2, %3" : "=v"(r) : "v"(a), "v"(b), "v"(c));
    return r;
}

__device__ __forceinline__ void gld_lds16(const uint16_t* g, uint16_t* l) {
    __builtin_amdgcn_global_load_lds(
        (const __attribute__((address_space(1))) void*)g,
        (__attribute__((address_space(3))) void*)l, 16, 0, 0);
}

// ---------------------------------------------------------------------------
// K1: cast query fp32 -> bf16   (8 elems/thread)
// ---------------------------------------------------------------------------
__global__ void cast_x_kernel(const float* __restrict__ x, uint16_t* __restrict__ out) {
    int g = blockIdx.x * 256 + threadIdx.x;
    const float4* xv = (const float4*)x;
    float4 a = xv[2 * g], b = xv[2 * g + 1];
    union { u32x4 v; uint16_t s[8]; } u;
    u.s[0] = f2b(a.x); u.s[1] = f2b(a.y); u.s[2] = f2b(a.z); u.s[3] = f2b(a.w);
    u.s[4] = f2b(b.x); u.s[5] = f2b(b.y); u.s[6] = f2b(b.z); u.s[7] = f2b(b.w);
    ((u32x4*)out)[g] = u.v;
}

// ---------------------------------------------------------------------------
// K2: build transposed bf16 weights Wt[n][k]; fold LoRA into wq/wv.
// ---------------------------------------------------------------------------
__global__ void make_wt_kernel(const float* __restrict__ wq, const float* __restrict__ wk,
                               const float* __restrict__ wv, const float* __restrict__ wo,
                               const float* __restrict__ Aq, const float* __restrict__ Bq,
                               const float* __restrict__ Av, const float* __restrict__ Bv,
                               uint16_t* __restrict__ Wt) {
    __shared__ float tile[64][65];
    int mat = blockIdx.z;
    int n0 = blockIdx.x * 64, k0 = blockIdx.y * 64;
    const float* W  = (mat == 0) ? wq : (mat == 1) ? wk : (mat == 2) ? wv : wo;
    const float* Ap = (mat == 0) ? Aq : (mat == 2) ? Av : nullptr;
    const float* Bp = (mat == 0) ? Bq : (mat == 2) ? Bv : nullptr;
    int t = threadIdx.x;
    int r = t >> 2, c0 = (t & 3) * 16;
    int k = k0 + r;
    #pragma unroll
    for (int j = 0; j < 16; j++) {
        int n = n0 + c0 + j;
        float v = W[(size_t)k * D_ + n];
        if (Ap) {
            float acc = 0.f;
            #pragma unroll
            for (int rr = 0; rr < R_; rr++) acc += Ap[k * R_ + rr] * Bp[rr * D_ + n];
            v += LORA_SCALE * acc;
        }
        tile[r][c0 + j] = v;
    }
    __syncthreads();
    int nl = t >> 2, ks = (t & 3) * 16;
    union { uint16_t s[16]; u32x4 v[2]; } uo;
    #pragma unroll
    for (int j = 0; j < 16; j++) uo.s[j] = f2b(tile[ks + j][nl]);
    uint16_t* dst = Wt + (size_t)mat * D_ * D_ + (size_t)(n0 + nl) * D_ + k0 + ks;
    *(u32x4*)&dst[0] = uo.v[0];
    *(u32x4*)&dst[8] = uo.v[1];
}

// ---------------------------------------------------------------------------
// K3/K7: C = A(MxK bf16, row-major) @ Bt(NxK bf16, row-major)^T
// ---------------------------------------------------------------------------
template <bool OUT_F32>
__global__ __launch_bounds__(256)
void gemm_bt_kernel(const uint16_t* __restrict__ A, const uint16_t* __restrict__ Bt,
                    uint16_t* __restrict__ Cb, float* __restrict__ Cf,
                    int Mdim, int Ndim, int Kdim) {
    __shared__ uint16_t At[128 * 32];
    __shared__ uint16_t Bs[128 * 32];
    int tid = threadIdx.x;
    int wave = tid >> 6, lane = tid & 63, quad = lane >> 4, l15 = lane & 15;
    int rowBase = blockIdx.y * 128, colBase = blockIdx.x * 128;
    int wRow = (wave >> 1) * 64, wCol = (wave & 1) * 64;
    int srow0 = tid >> 2, sseg0 = (tid & 3) * 8;
    int srow1 = (tid + 256) >> 2;
    f32x4 acc[4][4] = {};
    for (int kb = 0; kb < Kdim; kb += 32) {
        gld_lds16(&A [(size_t)(rowBase + srow0) * Kdim + kb + sseg0], &At[srow0 * 32 + sseg0]);
        gld_lds16(&A [(size_t)(rowBase + srow1) * Kdim + kb + sseg0], &At[srow1 * 32 + sseg0]);
        gld_lds16(&Bt[(size_t)(colBase + srow0) * Kdim + kb + sseg0], &Bs[srow0 * 32 + sseg0]);
        gld_lds16(&Bt[(size_t)(colBase + srow1) * Kdim + kb + sseg0], &Bs[srow1 * 32 + sseg0]);
        __syncthreads();
        bf16x8 af[4], bfr[4];
        #pragma unroll
        for (int m = 0; m < 4; m++) af[m]  = *(const bf16x8*)&At[(wRow + m * 16 + l15) * 32 + quad * 8];
        #pragma unroll
        for (int n = 0; n < 4; n++) bfr[n] = *(const bf16x8*)&Bs[(wCol + n * 16 + l15) * 32 + quad * 8];
        #pragma unroll
        for (int m = 0; m < 4; m++)
            #pragma unroll
            for (int n = 0; n < 4; n++)
                acc[m][n] = __builtin_amdgcn_mfma_f32_16x16x32_bf16(af[m], bfr[n], acc[m][n], 0, 0, 0);
        __syncthreads();
    }
    #pragma unroll
    for (int m = 0; m < 4; m++) {
        int row = rowBase + wRow + m * 16 + quad * 4;
        #pragma unroll
        for (int n = 0; n < 4; n++) {
            int col = colBase + wCol + n * 16 + l15;
            #pragma unroll
            for (int r = 0; r < 4; r++) {
                float v = acc[m][n][r];
                if (OUT_F32) Cf[(size_t)(row + r) * Ndim + col] = v;
                else         Cb[(size_t)(row + r) * Ndim + col] = f2b(v);
            }
        }
    }
}

// ---------------------------------------------------------------------------
// K4: RoPE on q,k; reshape (B,T,3D) -> (B,H,T,dh).
// Qr: linear (B,H,T,dh), PRE-SCALED by 1/sqrt(dh)*log2(e).
// Kr: SWIZZLED within each row: 16B chunk c of row t stored at chunk c^(t&7).
// ---------------------------------------------------------------------------
__global__ void rope_kernel(const uint16_t* __restrict__ qkv,
                            uint16_t* __restrict__ Qr, uint16_t* __restrict__ Kr) {
    int g = blockIdx.x * 256 + threadIdx.x;
    int i  = g & 31;
    int t  = (g >> 5) & (T_ - 1);
    int bh = g >> 16;
    int h = bh & 15, b = bh >> 4;
    size_t rowoff = ((size_t)(b * T_ + t)) * 3072 + h * 64 + 2 * i;
    uint32_t qp = *(const uint32_t*)&qkv[rowoff];
    uint32_t kp = *(const uint32_t*)&qkv[rowoff + 1024];
    float qe = b2f((uint16_t)qp), qo = b2f((uint16_t)(qp >> 16));
    float ke = b2f((uint16_t)kp), ko = b2f((uint16_t)(kp >> 16));
    float inv = exp2f(-(float)i * (13.2877123795494f / 32.f));
    float th = (float)t * inv;
    float s = sinf(th), c = cosf(th);
    const float SC = 0.125f * 1.44269504089f;   // 1/sqrt(64) * log2(e), folded into Q
    uint32_t qw = (uint32_t)f2b((qe * c - qo * s) * SC)
                | ((uint32_t)f2b((qe * s + qo * c) * SC) << 16);
    uint32_t kw = (uint32_t)f2b(ke * c - ko * s) | ((uint32_t)f2b(ke * s + ko * c) << 16);
    size_t o = ((size_t)bh * T_ + t) * 64 + 2 * i;
    *(uint32_t*)&Qr[o] = qw;
    int d = 2 * i;
    size_t kidx = ((size_t)bh * T_ + t) * 64 + ((((d >> 3) ^ (t & 7)) << 3) | (d & 7));
    *(uint32_t*)&Kr[kidx] = kw;
}

// ---------------------------------------------------------------------------
// K5: V -> Vt via LDS tile transpose.  64-t tiles so a 64-kpos chunk is
// CONTIGUOUS 4096 elems in global (verbatim DMA in attn).  Within each
// (64 d x 64 t) tile, 16B t-chunk c of d-row stored at c^(d&7):
// vidx = bh*64*T + (t>>6)*4096 + d*64 + phys*8.
// ---------------------------------------------------------------------------
__global__ void vtrans_kernel(const uint16_t* __restrict__ qkv, uint16_t* __restrict__ Vt) {
    __shared__ uint16_t tile[32][72];
    int bh = blockIdx.y, t0 = blockIdx.x * 32;
    int b = bh >> 4, h = bh & 15;
    int tid = threadIdx.x;
    int r = tid >> 3, c8 = (tid & 7) * 8;
    *(u32x4*)&tile[r][c8] =
        *(const u32x4*)&qkv[((size_t)(b * T_ + t0 + r)) * 3072 + 2048 + h * 64 + c8];
    __syncthreads();
    int d = tid >> 2, t8 = (tid & 3) * 8;
    union { uint16_t s[8]; u32x4 v; } uu;
    #pragma unroll
    for (int j = 0; j < 8; j++) uu.s[j] = tile[t8 + j][d];
    int tt = t0 + t8;
    int c  = (tt & 63) >> 3;
    int phys = (c ^ (d & 7)) & 7;
    size_t vidx = (size_t)bh * 64 * T_ + (size_t)(tt >> 6) * 4096 + d * 64 + phys * 8;
    *(u32x4*)&Vt[vidx] = uu.v;
}

// ---------------------------------------------------------------------------
// K6: causal flash attention, S^T orientation, chunk=64 kpos.
// LDS-PORT DIET: each wave now covers 32 q-rows (2 groups of 16) so every
// K fragment read feeds 4 MFMAs and every V fragment 2 MFMAs -- LDS-port
// cycles per FLOP cut ~40% (the measured limiter: ~74% port busy at r4).
// Blocks are 128 threads (2 waves = 64 q-rows); grid/staging identical to
// round 4 (verbatim DMA, swizzles in the Kr/Vt global layouts).
// LDS: K 8KB + V 8KB + P 9KB = 25.6KB -> 6 blocks/CU.
// ---------------------------------------------------------------------------
#define PSTR 72

__device__ __forceinline__ f32x4 mfma16(bf16x8 a, bf16x8 b, f32x4 c) {
    return __builtin_amdgcn_mfma_f32_16x16x32_bf16(a, b, c, 0, 0, 0);
}

// Two q-groups (g=0: rows q0w..q0w+15, g=1: rows q0w+16..q0w+31) share all
// K/V LDS reads.  MASKED (last chunk only): nact0 in {1,3}, nact1=nact0+1.
template <bool MASKED>
__device__ __forceinline__ void attn_chunk2(
    const uint16_t* __restrict__ Kst, const uint16_t* __restrict__ Vst,
    uint16_t* __restrict__ Pw, int nact0, int bkmq0,
    const bf16x8 (&aQ)[2][2], int l15, int quad,
    f32x4 (&Oacc)[2][4], float (&mrow)[2], float (&lrow)[2])
{
    int lx = l15 & 7;
    int nact1 = MASKED ? nact0 + 1 : 4;
    f32x4 sacc[2][4];
    if (MASKED) {                               // defined values on skipped tiles
        #pragma unroll
        for (int g = 0; g < 2; g++)
            #pragma unroll
            for (int n = 0; n < 4; n++) sacc[g][n] = f32x4{0.f, 0.f, 0.f, 0.f};
    }
    #pragma unroll
    for (int n = 0; n < 4; n++) {
        if (MASKED && n >= nact1) continue;
        int rowK = (n * 16 + l15) * 64;
        bf16x8 kv0 = *(const bf16x8*)&Kst[rowK + ((quad ^ lx) << 3)];
        bf16x8 kv1 = *(const bf16x8*)&Kst[rowK + (((quad + 4) ^ lx) << 3)];
        if (!MASKED || n < nact0) {
            f32x4 s = {};
            s = mfma16(kv0, aQ[0][0], s);
            s = mfma16(kv1, aQ[0][1], s);
            sacc[0][n] = s;
        }
        {
            f32x4 s = {};
            s = mfma16(kv0, aQ[1][0], s);
            s = mfma16(kv1, aQ[1][1], s);
            sacc[1][n] = s;
        }
    }
    // scores already scaled by 1/sqrt(dh)*log2e (folded into Q at rope time)
    #pragma unroll
    for (int g = 0; g < 2; g++) {
        int nag = MASKED ? (g ? nact1 : nact0) : 4;
        int bkm = bkmq0 - g * 16;
        float mx = -1e30f;
        #pragma unroll
        for (int n = 0; n < 4; n++) {
            if (MASKED && n >= nag) continue;
            if (MASKED) {
                #pragma unroll
                for (int r = 0; r < 4; r++) {
                    int kmq = bkm + n * 16 + quad * 4 + r;   // kpos - q
                    if (kmq > 0) sacc[g][n][r] = -1e30f;
                }
            }
            float t = max3f(sacc[g][n][0], sacc[g][n][1], sacc[g][n][2]);
            mx = max3f(mx, t, sacc[g][n][3]);
        }
        mx = fmaxf(mx, __shfl_xor(mx, 16, 64));
        mx = fmaxf(mx, __shfl_xor(mx, 32, 64));
        // defer-max (wave-uniform): P bounded by exp2(8)=256, safe in bf16.
        if (!__all(mx <= mrow[g] + 8.f)) {
            float mnew = fmaxf(mrow[g], mx);
            float alpha = exp2f(mrow[g] - mnew);
            #pragma unroll
            for (int m = 0; m < 4; m++)
                #pragma unroll
                for (int r = 0; r < 4; r++) Oacc[g][m][r] *= alpha;
            lrow[g] *= alpha;
            mrow[g] = mnew;
        }
        float sum = 0.f;
        #pragma unroll
        for (int n = 0; n < 4; n++) {
            if (MASKED && n >= nag) continue;
            #pragma unroll
            for (int r = 0; r < 4; r++) {
                float e = exp2f(sacc[g][n][r] - mrow[g]);
                sacc[g][n][r] = e;
                sum += e;
            }
        }
        sum += __shfl_xor(sum, 16, 64);
        sum += __shfl_xor(sum, 32, 64);
        lrow[g] += sum;
        // P^T -> wave-private LDS slab (rows g*16+l15)
        #pragma unroll
        for (int n = 0; n < 4; n++) {
            if (MASKED && n >= nag) continue;
            uint2 pk;
            pk.x = cvtpk(sacc[g][n][0], sacc[g][n][1]);
            pk.y = cvtpk(sacc[g][n][2], sacc[g][n][3]);
            *(uint2*)&Pw[(g * 16 + l15) * PSTR + n * 16 + quad * 4] = pk;
        }
        if (MASKED && (nag & 1)) {              // zero odd tail tile for b128 reads
            uint2 z; z.x = 0u; z.y = 0u;
            *(uint2*)&Pw[(g * 16 + l15) * PSTR + nag * 16 + quad * 4] = z;
        }
    }
    // PV: V fragments shared by both groups.  ssact identical for g=0,1
    // (nact0 odd, nact1=nact0+1 even -> (nact0+1)>>1 == nact1>>1).
    int ssact = MASKED ? ((nact1 + 1) >> 1) : 2;
    #pragma unroll
    for (int ss = 0; ss < 2; ss++) {
        if (MASKED && ss >= ssact) continue;
        bf16x8 bP0 = *(const bf16x8*)&Pw[l15 * PSTR + ss * 32 + quad * 8];
        bf16x8 bP1 = *(const bf16x8*)&Pw[(16 + l15) * PSTR + ss * 32 + quad * 8];
        int cl = ss * 4 + quad;
        int phys = (cl ^ lx) & 7;
        #pragma unroll
        for (int m = 0; m < 4; m++) {
            bf16x8 aV = *(const bf16x8*)&Vst[(m * 16 + l15) * 64 + (phys << 3)];
            Oacc[0][m] = mfma16(aV, bP0, Oacc[0][m]);
            Oacc[1][m] = mfma16(aV, bP1, Oacc[1][m]);
        }
    }
}

__global__ __launch_bounds__(128, 3)
void attn_kernel(const uint16_t* __restrict__ Qr, const uint16_t* __restrict__ Kr,
                 const uint16_t* __restrict__ Vt, uint16_t* __restrict__ Obuf) {
    __shared__ uint16_t KLDS[64 * 64];          // 8192 B, verbatim swizzled tile
    __shared__ uint16_t VLDS[64 * 64];          // 8192 B, verbatim swizzled tile
    __shared__ uint16_t Pl[2][32 * PSTR];       // 9216 B, wave-private slabs
    // XCD swizzle: 8 bh resident per XCD (K/V L2-local); heavy q-tiles first.
    int id  = blockIdx.x;
    int xcd = id & 7, grp = id >> 3;
    int bh  = xcd * 8 + (grp & 7);
    int qt  = 31 - (grp >> 3);                  // 31..0, heavy first
    int b = bh >> 4, h = bh & 15;
    int tid = threadIdx.x, wave = tid >> 6, lane = tid & 63, quad = lane >> 4, l15 = lane & 15;
    const uint16_t* Qbase = Qr + (size_t)bh * T_ * 64;
    const uint16_t* Kbase = Kr + (size_t)bh * T_ * 64;
    const uint16_t* Vbase = Vt + (size_t)bh * 64 * T_;
    uint16_t* Pw = &Pl[wave][0];
    int q0w = qt * 64 + wave * 32;              // wave covers rows q0w..q0w+31
    bf16x8 aQ[2][2];
    #pragma unroll
    for (int g = 0; g < 2; g++) {
        aQ[g][0] = *(const bf16x8*)&Qbase[(size_t)(q0w + g * 16 + l15) * 64 + quad * 8];
        aQ[g][1] = *(const bf16x8*)&Qbase[(size_t)(q0w + g * 16 + l15) * 64 + 32 + quad * 8];
    }
    f32x4 Oacc[2][4] = {};
    float mrow[2] = {-1e30f, -1e30f}, lrow[2] = {0.f, 0.f};
    int nch = qt + 1;                           // 64-kpos chunks, uniform across waves
    for (int c = 0; c < nch; c++) {
        int k0 = c * 64;
        __syncthreads();                        // (a) all waves done with prev K/V LDS
        const uint16_t* gK = Kbase + (size_t)k0 * 64;       // contiguous swizzled tile
        const uint16_t* gV = Vbase + (size_t)(k0 >> 6) * 4096;
        #pragma unroll
        for (int j = 0; j < 4; j++) {
            gld_lds16(gK + (tid + j * 128) * 8, &KLDS[(tid + j * 128) * 8]);
            gld_lds16(gV + (tid + j * 128) * 8, &VLDS[(tid + j * 128) * 8]);
        }
        __syncthreads();                        // (b) DMA drained + visible
        if (c == nch - 1) {
            // last chunk is masked for BOTH waves: k0 = qt*64, so
            // wave0: nact0=1,nact1=2;  wave1: nact0=3,nact1=4.
            int nact0 = ((q0w + 15 - k0) >> 4) + 1;
            attn_chunk2<true>(KLDS, VLDS, Pw, nact0, k0 - q0w - l15,
                              aQ, l15, quad, Oacc, mrow, lrow);
        } else {
            attn_chunk2<false>(KLDS, VLDS, Pw, 0, 0,
                               aQ, l15, quad, Oacc, mrow, lrow);
        }
    }
    // epilogue: direct register -> global stores per group.
    #pragma unroll
    for (int g = 0; g < 2; g++) {
        float invl = 1.0f / lrow[g];
        size_t obase = ((size_t)(b * T_ + q0w + g * 16 + l15)) * D_ + h * 64;
        #pragma unroll
        for (int m = 0; m < 4; m++) {
            uint2 ob;
            ob.x = cvtpk(Oacc[g][m][0] * invl, Oacc[g][m][1] * invl);
            ob.y = cvtpk(Oacc[g][m][2] * invl, Oacc[g][m][3] * invl);
            *(uint2*)&Obuf[obase + m * 16 + quad * 4] = ob;
        }
    }
}

// ---------------------------------------------------------------------------
extern "C" void kernel_launch(void* const* d_in, const int* in_sizes, int n_in,
                              void* d_out, int out_size, void* d_ws, size_t ws_size,
                              hipStream_t stream) {
    const float* query = (const float*)d_in[0];
    const float* wq = (const float*)d_in[1];
    const float* wk = (const float*)d_in[2];
    const float* wv = (const float*)d_in[3];
    const float* wo = (const float*)d_in[4];
    const float* Aq = (const float*)d_in[5];
    const float* Bq = (const float*)d_in[6];
    const float* Av = (const float*)d_in[7];
    const float* Bv = (const float*)d_in[8];
    float* out = (float*)d_out;

    const size_t MB = 1ull << 20;
    if (ws_size < 120 * MB) return;
    char* ws = (char*)d_ws;
    uint16_t* Xbf = (uint16_t*)(ws);                   // 16 MB
    uint16_t* Wt  = (uint16_t*)(ws + 16 * MB);         //  8 MB
    uint16_t* qkv = (uint16_t*)(ws + 24 * MB);         // 48 MB
    uint16_t* Qr  = (uint16_t*)(ws + 72 * MB);         // 16 MB (pre-scaled)
    uint16_t* Kr  = (uint16_t*)(ws + 88 * MB);         // 16 MB (row-swizzled)
    uint16_t* Vt  = (uint16_t*)(ws + 104 * MB);        // 16 MB (64-t tile-swizzled)
    uint16_t* Obuf = qkv;                              // reuse (dead after rope/vtrans)

    cast_x_kernel<<<4096, 256, 0, stream>>>(query, Xbf);
    make_wt_kernel<<<dim3(16, 16, 4), 256, 0, stream>>>(wq, wk, wv, wo, Aq, Bq, Av, Bv, Wt);
    gemm_bt_kernel<false><<<dim3(3072 / 128, M_ / 128), 256, 0, stream>>>(
        Xbf, Wt, qkv, nullptr, M_, 3072, D_);
    rope_kernel<<<16384, 256, 0, stream>>>(qkv, Qr, Kr);
    vtrans_kernel<<<dim3(T_ / 32, B_ * H_), 256, 0, stream>>>(qkv, Vt);
    attn_kernel<<<2048, 128, 0, stream>>>(Qr, Kr, Vt, Obuf);
    gemm_bt_kernel<true><<<dim3(D_ / 128, M_ / 128), 256, 0, stream>>>(
        Obuf, Wt + 3ull * D_ * D_, nullptr, out, M_, D_, D_);
}

// Round 6
// 313.853 us; speedup vs baseline: 1.0094x; 1.0094x over previous
//
#include <hip/hip_runtime.h>
#include <cstdint>

// Problem constants
#define B_  4
#define T_  2048
#define D_  1024
#define H_  16
#define DH_ 64
#define R_  8
#define M_  (B_*T_)          // 8192
#define LORA_SCALE 4.0f

typedef __attribute__((ext_vector_type(8))) short    bf16x8;
typedef __attribute__((ext_vector_type(4))) short    bf16x4;
typedef __attribute__((ext_vector_type(4))) float    f32x4;
typedef __attribute__((ext_vector_type(4))) uint32_t u32x4;

__device__ inline uint16_t f2b(float f) {             // fp32 -> bf16 RNE
    uint32_t x = __float_as_uint(f);
    return (uint16_t)((x + 0x7fffu + ((x >> 16) & 1u)) >> 16);
}
__device__ inline float b2f(uint16_t u) { return __uint_as_float(((uint32_t)u) << 16); }

// packed f32x2 -> bf16x2 (no builtin on gfx950; pure VOP3 asm, schedulable)
__device__ __forceinline__ uint32_t cvtpk(float lo, float hi) {
    uint32_t r;
    asm("v_cvt_pk_bf16_f32 %0, %1, %2" : "=v"(r) : "v"(lo), "v"(hi));
    return r;
}
__device__ __forceinline__ float max3f(float a, float b, float c) {
    float r;
    asm("v_max3_f32 %0, %1, %2, %3" : "=v"(r) : "v"(a), "v"(b), "v"(c));
    return r;
}

__device__ __forceinline__ void gld_lds16(const uint16_t* g, uint16_t* l) {
    __builtin_amdgcn_global_load_lds(
        (const __attribute__((address_space(1))) void*)g,
        (__attribute__((address_space(3))) void*)l, 16, 0, 0);
}

// ---------------------------------------------------------------------------
// K1: cast query fp32 -> bf16   (8 elems/thread)
// ---------------------------------------------------------------------------
__global__ void cast_x_kernel(const float* __restrict__ x, uint16_t* __restrict__ out) {
    int g = blockIdx.x * 256 + threadIdx.x;
    const float4* xv = (const float4*)x;
    float4 a = xv[2 * g], b = xv[2 * g + 1];
    union { u32x4 v; uint16_t s[8]; } u;
    u.s[0] = f2b(a.x); u.s[1] = f2b(a.y); u.s[2] = f2b(a.z); u.s[3] = f2b(a.w);
    u.s[4] = f2b(b.x); u.s[5] = f2b(b.y); u.s[6] = f2b(b.z); u.s[7] = f2b(b.w);
    ((u32x4*)out)[g] = u.v;
}

// ---------------------------------------------------------------------------
// K2: build transposed bf16 weights Wt[n][k]; fold LoRA into wq/wv.
// ---------------------------------------------------------------------------
__global__ void make_wt_kernel(const float* __restrict__ wq, const float* __restrict__ wk,
                               const float* __restrict__ wv, const float* __restrict__ wo,
                               const float* __restrict__ Aq, const float* __restrict__ Bq,
                               const float* __restrict__ Av, const float* __restrict__ Bv,
                               uint16_t* __restrict__ Wt) {
    __shared__ float tile[64][65];
    int mat = blockIdx.z;
    int n0 = blockIdx.x * 64, k0 = blockIdx.y * 64;
    const float* W  = (mat == 0) ? wq : (mat == 1) ? wk : (mat == 2) ? wv : wo;
    const float* Ap = (mat == 0) ? Aq : (mat == 2) ? Av : nullptr;
    const float* Bp = (mat == 0) ? Bq : (mat == 2) ? Bv : nullptr;
    int t = threadIdx.x;
    int r = t >> 2, c0 = (t & 3) * 16;
    int k = k0 + r;
    #pragma unroll
    for (int j = 0; j < 16; j++) {
        int n = n0 + c0 + j;
        float v = W[(size_t)k * D_ + n];
        if (Ap) {
            float acc = 0.f;
            #pragma unroll
            for (int rr = 0; rr < R_; rr++) acc += Ap[k * R_ + rr] * Bp[rr * D_ + n];
            v += LORA_SCALE * acc;
        }
        tile[r][c0 + j] = v;
    }
    __syncthreads();
    int nl = t >> 2, ks = (t & 3) * 16;
    union { uint16_t s[16]; u32x4 v[2]; } uo;
    #pragma unroll
    for (int j = 0; j < 16; j++) uo.s[j] = f2b(tile[ks + j][nl]);
    uint16_t* dst = Wt + (size_t)mat * D_ * D_ + (size_t)(n0 + nl) * D_ + k0 + ks;
    *(u32x4*)&dst[0] = uo.v[0];
    *(u32x4*)&dst[8] = uo.v[1];
}

// ---------------------------------------------------------------------------
// K3/K7: C = A(MxK bf16, row-major) @ Bt(NxK bf16, row-major)^T
// ---------------------------------------------------------------------------
template <bool OUT_F32>
__global__ __launch_bounds__(256)
void gemm_bt_kernel(const uint16_t* __restrict__ A, const uint16_t* __restrict__ Bt,
                    uint16_t* __restrict__ Cb, float* __restrict__ Cf,
                    int Mdim, int Ndim, int Kdim) {
    __shared__ uint16_t At[128 * 32];
    __shared__ uint16_t Bs[128 * 32];
    int tid = threadIdx.x;
    int wave = tid >> 6, lane = tid & 63, quad = lane >> 4, l15 = lane & 15;
    int rowBase = blockIdx.y * 128, colBase = blockIdx.x * 128;
    int wRow = (wave >> 1) * 64, wCol = (wave & 1) * 64;
    int srow0 = tid >> 2, sseg0 = (tid & 3) * 8;
    int srow1 = (tid + 256) >> 2;
    f32x4 acc[4][4] = {};
    for (int kb = 0; kb < Kdim; kb += 32) {
        gld_lds16(&A [(size_t)(rowBase + srow0) * Kdim + kb + sseg0], &At[srow0 * 32 + sseg0]);
        gld_lds16(&A [(size_t)(rowBase + srow1) * Kdim + kb + sseg0], &At[srow1 * 32 + sseg0]);
        gld_lds16(&Bt[(size_t)(colBase + srow0) * Kdim + kb + sseg0], &Bs[srow0 * 32 + sseg0]);
        gld_lds16(&Bt[(size_t)(colBase + srow1) * Kdim + kb + sseg0], &Bs[srow1 * 32 + sseg0]);
        __syncthreads();
        bf16x8 af[4], bfr[4];
        #pragma unroll
        for (int m = 0; m < 4; m++) af[m]  = *(const bf16x8*)&At[(wRow + m * 16 + l15) * 32 + quad * 8];
        #pragma unroll
        for (int n = 0; n < 4; n++) bfr[n] = *(const bf16x8*)&Bs[(wCol + n * 16 + l15) * 32 + quad * 8];
        #pragma unroll
        for (int m = 0; m < 4; m++)
            #pragma unroll
            for (int n = 0; n < 4; n++)
                acc[m][n] = __builtin_amdgcn_mfma_f32_16x16x32_bf16(af[m], bfr[n], acc[m][n], 0, 0, 0);
        __syncthreads();
    }
    #pragma unroll
    for (int m = 0; m < 4; m++) {
        int row = rowBase + wRow + m * 16 + quad * 4;
        #pragma unroll
        for (int n = 0; n < 4; n++) {
            int col = colBase + wCol + n * 16 + l15;
            #pragma unroll
            for (int r = 0; r < 4; r++) {
                float v = acc[m][n][r];
                if (OUT_F32) Cf[(size_t)(row + r) * Ndim + col] = v;
                else         Cb[(size_t)(row + r) * Ndim + col] = f2b(v);
            }
        }
    }
}

// ---------------------------------------------------------------------------
// K4: RoPE on q,k; reshape (B,T,3D) -> (B,H,T,dh).
// Qr: linear (B,H,T,dh), PRE-SCALED by 1/sqrt(dh)*log2(e).
// Kr: SWIZZLED within each row: 16B chunk c of row t stored at chunk c^(t&7).
// ---------------------------------------------------------------------------
__global__ void rope_kernel(const uint16_t* __restrict__ qkv,
                            uint16_t* __restrict__ Qr, uint16_t* __restrict__ Kr) {
    int g = blockIdx.x * 256 + threadIdx.x;
    int i  = g & 31;
    int t  = (g >> 5) & (T_ - 1);
    int bh = g >> 16;
    int h = bh & 15, b = bh >> 4;
    size_t rowoff = ((size_t)(b * T_ + t)) * 3072 + h * 64 + 2 * i;
    uint32_t qp = *(const uint32_t*)&qkv[rowoff];
    uint32_t kp = *(const uint32_t*)&qkv[rowoff + 1024];
    float qe = b2f((uint16_t)qp), qo = b2f((uint16_t)(qp >> 16));
    float ke = b2f((uint16_t)kp), ko = b2f((uint16_t)(kp >> 16));
    float inv = exp2f(-(float)i * (13.2877123795494f / 32.f));
    float th = (float)t * inv;
    float s = sinf(th), c = cosf(th);
    const float SC = 0.125f * 1.44269504089f;   // 1/sqrt(64) * log2(e), folded into Q
    uint32_t qw = (uint32_t)f2b((qe * c - qo * s) * SC)
                | ((uint32_t)f2b((qe * s + qo * c) * SC) << 16);
    uint32_t kw = (uint32_t)f2b(ke * c - ko * s) | ((uint32_t)f2b(ke * s + ko * c) << 16);
    size_t o = ((size_t)bh * T_ + t) * 64 + 2 * i;
    *(uint32_t*)&Qr[o] = qw;
    int d = 2 * i;
    size_t kidx = ((size_t)bh * T_ + t) * 64 + ((((d >> 3) ^ (t & 7)) << 3) | (d & 7));
    *(uint32_t*)&Kr[kidx] = kw;
}

// ---------------------------------------------------------------------------
// K5: V -> Vt via LDS tile transpose.  64-t tiles so a 64-kpos chunk is
// CONTIGUOUS 4096 elems in global (verbatim DMA in attn).  Within each
// (64 d x 64 t) tile, 16B t-chunk c of d-row stored at c^(d&7):
// vidx = bh*64*T + (t>>6)*4096 + d*64 + phys*8.
// ---------------------------------------------------------------------------
__global__ void vtrans_kernel(const uint16_t* __restrict__ qkv, uint16_t* __restrict__ Vt) {
    __shared__ uint16_t tile[32][72];
    int bh = blockIdx.y, t0 = blockIdx.x * 32;
    int b = bh >> 4, h = bh & 15;
    int tid = threadIdx.x;
    int r = tid >> 3, c8 = (tid & 7) * 8;
    *(u32x4*)&tile[r][c8] =
        *(const u32x4*)&qkv[((size_t)(b * T_ + t0 + r)) * 3072 + 2048 + h * 64 + c8];
    __syncthreads();
    int d = tid >> 2, t8 = (tid & 3) * 8;
    union { uint16_t s[8]; u32x4 v; } uu;
    #pragma unroll
    for (int j = 0; j < 8; j++) uu.s[j] = tile[t8 + j][d];
    int tt = t0 + t8;
    int c  = (tt & 63) >> 3;
    int phys = (c ^ (d & 7)) & 7;
    size_t vidx = (size_t)bh * 64 * T_ + (size_t)(tt >> 6) * 4096 + d * 64 + phys * 8;
    *(u32x4*)&Vt[vidx] = uu.v;
}

// ---------------------------------------------------------------------------
// K6: causal flash attention, S^T orientation, chunk=64 kpos.
// Round-6 structure: 256-thread blocks (4 waves -- round-4's proven
// latency-hiding shell) x 32 q-rows PER WAVE (round-5's LDS-port
// amortization: each K fragment feeds 4 MFMAs, each V fragment 2).
// Block covers 128 q-rows -> grid 1024 = 4 blocks/CU; chunk stagings,
// barriers and K/V LDS reads per unit work are HALVED vs round 4.
// LDS: K 8KB + V 8KB + P 18KB = 34.8KB -> 4 blocks/CU.
// ---------------------------------------------------------------------------
#define PSTR 72

__device__ __forceinline__ f32x4 mfma16(bf16x8 a, bf16x8 b, f32x4 c) {
    return __builtin_amdgcn_mfma_f32_16x16x32_bf16(a, b, c, 0, 0, 0);
}

// Two q-groups (g=0: rows q0w..q0w+15, g=1: rows q0w+16..q0w+31) share all
// K/V LDS reads.  MASKED (each wave's final chunk): nact0 odd, nact1=nact0+1.
template <bool MASKED>
__device__ __forceinline__ void attn_chunk2(
    const uint16_t* __restrict__ Kst, const uint16_t* __restrict__ Vst,
    uint16_t* __restrict__ Pw, int nact0, int bkmq0,
    const bf16x8 (&aQ)[2][2], int l15, int quad,
    f32x4 (&Oacc)[2][4], float (&mrow)[2], float (&lrow)[2])
{
    int lx = l15 & 7;
    int nact1 = MASKED ? nact0 + 1 : 4;
    f32x4 sacc[2][4];
    if (MASKED) {                               // defined values on skipped tiles
        #pragma unroll
        for (int g = 0; g < 2; g++)
            #pragma unroll
            for (int n = 0; n < 4; n++) sacc[g][n] = f32x4{0.f, 0.f, 0.f, 0.f};
    }
    #pragma unroll
    for (int n = 0; n < 4; n++) {
        if (MASKED && n >= nact1) continue;
        int rowK = (n * 16 + l15) * 64;
        bf16x8 kv0 = *(const bf16x8*)&Kst[rowK + ((quad ^ lx) << 3)];
        bf16x8 kv1 = *(const bf16x8*)&Kst[rowK + (((quad + 4) ^ lx) << 3)];
        if (!MASKED || n < nact0) {
            f32x4 s = {};
            s = mfma16(kv0, aQ[0][0], s);
            s = mfma16(kv1, aQ[0][1], s);
            sacc[0][n] = s;
        }
        {
            f32x4 s = {};
            s = mfma16(kv0, aQ[1][0], s);
            s = mfma16(kv1, aQ[1][1], s);
            sacc[1][n] = s;
        }
    }
    // scores already scaled by 1/sqrt(dh)*log2e (folded into Q at rope time)
    #pragma unroll
    for (int g = 0; g < 2; g++) {
        int nag = MASKED ? (g ? nact1 : nact0) : 4;
        int bkm = bkmq0 - g * 16;
        float mx = -1e30f;
        #pragma unroll
        for (int n = 0; n < 4; n++) {
            if (MASKED && n >= nag) continue;
            if (MASKED) {
                #pragma unroll
                for (int r = 0; r < 4; r++) {
                    int kmq = bkm + n * 16 + quad * 4 + r;   // kpos - q
                    if (kmq > 0) sacc[g][n][r] = -1e30f;
                }
            }
            float t = max3f(sacc[g][n][0], sacc[g][n][1], sacc[g][n][2]);
            mx = max3f(mx, t, sacc[g][n][3]);
        }
        mx = fmaxf(mx, __shfl_xor(mx, 16, 64));
        mx = fmaxf(mx, __shfl_xor(mx, 32, 64));
        // defer-max (wave-uniform): P bounded by exp2(8)=256, safe in bf16.
        if (!__all(mx <= mrow[g] + 8.f)) {
            float mnew = fmaxf(mrow[g], mx);
            float alpha = exp2f(mrow[g] - mnew);
            #pragma unroll
            for (int m = 0; m < 4; m++)
                #pragma unroll
                for (int r = 0; r < 4; r++) Oacc[g][m][r] *= alpha;
            lrow[g] *= alpha;
            mrow[g] = mnew;
        }
        float sum = 0.f;
        #pragma unroll
        for (int n = 0; n < 4; n++) {
            if (MASKED && n >= nag) continue;
            #pragma unroll
            for (int r = 0; r < 4; r++) {
                float e = exp2f(sacc[g][n][r] - mrow[g]);
                sacc[g][n][r] = e;
                sum += e;
            }
        }
        sum += __shfl_xor(sum, 16, 64);
        sum += __shfl_xor(sum, 32, 64);
        lrow[g] += sum;
        // P^T -> wave-private LDS slab (rows g*16+l15)
        #pragma unroll
        for (int n = 0; n < 4; n++) {
            if (MASKED && n >= nag) continue;
            uint2 pk;
            pk.x = cvtpk(sacc[g][n][0], sacc[g][n][1]);
            pk.y = cvtpk(sacc[g][n][2], sacc[g][n][3]);
            *(uint2*)&Pw[(g * 16 + l15) * PSTR + n * 16 + quad * 4] = pk;
        }
        if (MASKED && (nag & 1)) {              // zero odd tail tile for b128 reads
            uint2 z; z.x = 0u; z.y = 0u;
            *(uint2*)&Pw[(g * 16 + l15) * PSTR + nag * 16 + quad * 4] = z;
        }
    }
    // PV: V fragments shared by both groups.  ssact identical for g=0,1
    // (nact0 odd, nact1=nact0+1 even -> (nact0+1)>>1 == nact1>>1).
    int ssact = MASKED ? ((nact1 + 1) >> 1) : 2;
    #pragma unroll
    for (int ss = 0; ss < 2; ss++) {
        if (MASKED && ss >= ssact) continue;
        bf16x8 bP0 = *(const bf16x8*)&Pw[l15 * PSTR + ss * 32 + quad * 8];
        bf16x8 bP1 = *(const bf16x8*)&Pw[(16 + l15) * PSTR + ss * 32 + quad * 8];
        int cl = ss * 4 + quad;
        int phys = (cl ^ lx) & 7;
        #pragma unroll
        for (int m = 0; m < 4; m++) {
            bf16x8 aV = *(const bf16x8*)&Vst[(m * 16 + l15) * 64 + (phys << 3)];
            Oacc[0][m] = mfma16(aV, bP0, Oacc[0][m]);
            Oacc[1][m] = mfma16(aV, bP1, Oacc[1][m]);
        }
    }
}

__global__ __launch_bounds__(256, 4)
void attn_kernel(const uint16_t* __restrict__ Qr, const uint16_t* __restrict__ Kr,
                 const uint16_t* __restrict__ Vt, uint16_t* __restrict__ Obuf) {
    __shared__ uint16_t KLDS[64 * 64];          // 8192 B, verbatim swizzled tile
    __shared__ uint16_t VLDS[64 * 64];          // 8192 B, verbatim swizzled tile
    __shared__ uint16_t Pl[4][32 * PSTR];       // 18432 B, wave-private slabs
    // XCD swizzle: 8 bh resident per XCD (K/V L2-local); heavy q-tiles first.
    int id  = blockIdx.x;                       // 0..1023
    int xcd = id & 7, grp = id >> 3;
    int bh  = xcd * 8 + (grp & 7);
    int qt  = 15 - (grp >> 3);                  // 15..0 (128-row tiles), heavy first
    int b = bh >> 4, h = bh & 15;
    int tid = threadIdx.x, wave = tid >> 6, lane = tid & 63, quad = lane >> 4, l15 = lane & 15;
    const uint16_t* Qbase = Qr + (size_t)bh * T_ * 64;
    const uint16_t* Kbase = Kr + (size_t)bh * T_ * 64;
    const uint16_t* Vbase = Vt + (size_t)bh * 64 * T_;
    uint16_t* Pw = &Pl[wave][0];
    int q0w = qt * 128 + wave * 32;             // wave covers rows q0w..q0w+31
    bf16x8 aQ[2][2];
    #pragma unroll
    for (int g = 0; g < 2; g++) {
        aQ[g][0] = *(const bf16x8*)&Qbase[(size_t)(q0w + g * 16 + l15) * 64 + quad * 8];
        aQ[g][1] = *(const bf16x8*)&Qbase[(size_t)(q0w + g * 16 + l15) * 64 + 32 + quad * 8];
    }
    f32x4 Oacc[2][4] = {};
    float mrow[2] = {-1e30f, -1e30f}, lrow[2] = {0.f, 0.f};
    int nch = 2 * qt + 2;                       // 64-kpos chunks for the whole block
    int cm  = 2 * qt + (wave >> 1);             // this wave's (only) masked chunk
    int idx0 = tid, idx1 = tid + 256;
    for (int c = 0; c < nch; c++) {
        int k0 = c * 64;
        __syncthreads();                        // (a) all waves done with prev K/V LDS
        const uint16_t* gK = Kbase + (size_t)k0 * 64;       // contiguous swizzled tile
        const uint16_t* gV = Vbase + (size_t)(k0 >> 6) * 4096;
        gld_lds16(gK + idx0 * 8, &KLDS[idx0 * 8]);
        gld_lds16(gK + idx1 * 8, &KLDS[idx1 * 8]);
        gld_lds16(gV + idx0 * 8, &VLDS[idx0 * 8]);
        gld_lds16(gV + idx1 * 8, &VLDS[idx1 * 8]);
        __syncthreads();                        // (b) DMA drained + visible
        if (c < cm) {                           // fully unmasked for this wave
            attn_chunk2<false>(KLDS, VLDS, Pw, 0, 0,
                               aQ, l15, quad, Oacc, mrow, lrow);
        } else if (c == cm) {                   // masked tail chunk for this wave
            int nact0 = ((q0w + 15 - k0) >> 4) + 1;   // 1 or 3
            attn_chunk2<true>(KLDS, VLDS, Pw, nact0, k0 - q0w - l15,
                              aQ, l15, quad, Oacc, mrow, lrow);
        }                                       // c > cm: dead (waves 0/1), barriers only
    }
    // epilogue: direct register -> global stores per group.
    #pragma unroll
    for (int g = 0; g < 2; g++) {
        float invl = 1.0f / lrow[g];
        size_t obase = ((size_t)(b * T_ + q0w + g * 16 + l15)) * D_ + h * 64;
        #pragma unroll
        for (int m = 0; m < 4; m++) {
            uint2 ob;
            ob.x = cvtpk(Oacc[g][m][0] * invl, Oacc[g][m][1] * invl);
            ob.y = cvtpk(Oacc[g][m][2] * invl, Oacc[g][m][3] * invl);
            *(uint2*)&Obuf[obase + m * 16 + quad * 4] = ob;
        }
    }
}

// ---------------------------------------------------------------------------
extern "C" void kernel_launch(void* const* d_in, const int* in_sizes, int n_in,
                              void* d_out, int out_size, void* d_ws, size_t ws_size,
                              hipStream_t stream) {
    const float* query = (const float*)d_in[0];
    const float* wq = (const float*)d_in[1];
    const float* wk = (const float*)d_in[2];
    const float* wv = (const float*)d_in[3];
    const float* wo = (const float*)d_in[4];
    const float* Aq = (const float*)d_in[5];
    const float* Bq = (const float*)d_in[6];
    const float* Av = (const float*)d_in[7];
    const float* Bv = (const float*)d_in[8];
    float* out = (float*)d_out;

    const size_t MB = 1ull << 20;
    if (ws_size < 120 * MB) return;
    char* ws = (char*)d_ws;
    uint16_t* Xbf = (uint16_t*)(ws);                   // 16 MB
    uint16_t* Wt  = (uint16_t*)(ws + 16 * MB);         //  8 MB
    uint16_t* qkv = (uint16_t*)(ws + 24 * MB);         // 48 MB
    uint16_t* Qr  = (uint16_t*)(ws + 72 * MB);         // 16 MB (pre-scaled)
    uint16_t* Kr  = (uint16_t*)(ws + 88 * MB);         // 16 MB (row-swizzled)
    uint16_t* Vt  = (uint16_t*)(ws + 104 * MB);        // 16 MB (64-t tile-swizzled)
    uint16_t* Obuf = qkv;                              // reuse (dead after rope/vtrans)

    cast_x_kernel<<<4096, 256, 0, stream>>>(query, Xbf);
    make_wt_kernel<<<dim3(16, 16, 4), 256, 0, stream>>>(wq, wk, wv, wo, Aq, Bq, Av, Bv, Wt);
    gemm_bt_kernel<false><<<dim3(3072 / 128, M_ / 128), 256, 0, stream>>>(
        Xbf, Wt, qkv, nullptr, M_, 3072, D_);
    rope_kernel<<<16384, 256, 0, stream>>>(qkv, Qr, Kr);
    vtrans_kernel<<<dim3(T_ / 32, B_ * H_), 256, 0, stream>>>(qkv, Vt);
    attn_kernel<<<1024, 256, 0, stream>>>(Qr, Kr, Vt, Obuf);
    gemm_bt_kernel<true><<<dim3(D_ / 128, M_ / 128), 256, 0, stream>>>(
        Obuf, Wt + 3ull * D_ * D_, nullptr, out, M_, D_, D_);
}

// Round 9
// 302.263 us; speedup vs baseline: 1.0481x; 1.0383x over previous
//
#include <hip/hip_runtime.h>
#include <cstdint>

// Problem constants
#define B_  4
#define T_  2048
#define D_  1024
#define H_  16
#define DH_ 64
#define R_  8
#define M_  (B_*T_)          // 8192
#define LORA_SCALE 4.0f

typedef __attribute__((ext_vector_type(8))) short    bf16x8;
typedef __attribute__((ext_vector_type(4))) short    bf16x4;
typedef __attribute__((ext_vector_type(4))) float    f32x4;
typedef __attribute__((ext_vector_type(4))) uint32_t u32x4;

__device__ inline uint16_t f2b(float f) {             // fp32 -> bf16 RNE
    uint32_t x = __float_as_uint(f);
    return (uint16_t)((x + 0x7fffu + ((x >> 16) & 1u)) >> 16);
}
__device__ inline float b2f(uint16_t u) { return __uint_as_float(((uint32_t)u) << 16); }

// packed f32x2 -> bf16x2 (no builtin on gfx950; pure VOP3 asm, schedulable)
__device__ __forceinline__ uint32_t cvtpk(float lo, float hi) {
    uint32_t r;
    asm("v_cvt_pk_bf16_f32 %0, %1, %2" : "=v"(r) : "v"(lo), "v"(hi));
    return r;
}
__device__ __forceinline__ float max3f(float a, float b, float c) {
    float r;
    asm("v_max3_f32 %0, %1, %2, %3" : "=v"(r) : "v"(a), "v"(b), "v"(c));
    return r;
}

__device__ __forceinline__ void gld_lds16(const uint16_t* g, uint16_t* l) {
    __builtin_amdgcn_global_load_lds(
        (const __attribute__((address_space(1))) void*)g,
        (__attribute__((address_space(3))) void*)l, 16, 0, 0);
}

// ---------------------------------------------------------------------------
// K1: cast query fp32 -> bf16   (8 elems/thread)
// ---------------------------------------------------------------------------
__global__ void cast_x_kernel(const float* __restrict__ x, uint16_t* __restrict__ out) {
    int g = blockIdx.x * 256 + threadIdx.x;
    const float4* xv = (const float4*)x;
    float4 a = xv[2 * g], b = xv[2 * g + 1];
    union { u32x4 v; uint16_t s[8]; } u;
    u.s[0] = f2b(a.x); u.s[1] = f2b(a.y); u.s[2] = f2b(a.z); u.s[3] = f2b(a.w);
    u.s[4] = f2b(b.x); u.s[5] = f2b(b.y); u.s[6] = f2b(b.z); u.s[7] = f2b(b.w);
    ((u32x4*)out)[g] = u.v;
}

// ---------------------------------------------------------------------------
// K2: build transposed bf16 weights Wt[n][k]; fold LoRA into wq/wv.
// ---------------------------------------------------------------------------
__global__ void make_wt_kernel(const float* __restrict__ wq, const float* __restrict__ wk,
                               const float* __restrict__ wv, const float* __restrict__ wo,
                               const float* __restrict__ Aq, const float* __restrict__ Bq,
                               const float* __restrict__ Av, const float* __restrict__ Bv,
                               uint16_t* __restrict__ Wt) {
    __shared__ float tile[64][65];
    int mat = blockIdx.z;
    int n0 = blockIdx.x * 64, k0 = blockIdx.y * 64;
    const float* W  = (mat == 0) ? wq : (mat == 1) ? wk : (mat == 2) ? wv : wo;
    const float* Ap = (mat == 0) ? Aq : (mat == 2) ? Av : nullptr;
    const float* Bp = (mat == 0) ? Bq : (mat == 2) ? Bv : nullptr;
    int t = threadIdx.x;
    int r = t >> 2, c0 = (t & 3) * 16;
    int k = k0 + r;
    #pragma unroll
    for (int j = 0; j < 16; j++) {
        int n = n0 + c0 + j;
        float v = W[(size_t)k * D_ + n];
        if (Ap) {
            float acc = 0.f;
            #pragma unroll
            for (int rr = 0; rr < R_; rr++) acc += Ap[k * R_ + rr] * Bp[rr * D_ + n];
            v += LORA_SCALE * acc;
        }
        tile[r][c0 + j] = v;
    }
    __syncthreads();
    int nl = t >> 2, ks = (t & 3) * 16;
    union { uint16_t s[16]; u32x4 v[2]; } uo;
    #pragma unroll
    for (int j = 0; j < 16; j++) uo.s[j] = f2b(tile[ks + j][nl]);
    uint16_t* dst = Wt + (size_t)mat * D_ * D_ + (size_t)(n0 + nl) * D_ + k0 + ks;
    *(u32x4*)&dst[0] = uo.v[0];
    *(u32x4*)&dst[8] = uo.v[1];
}

// ---------------------------------------------------------------------------
// K3/K7: C = A(MxK bf16, row-major) @ Bt(NxK bf16, row-major)^T
// T1 XCD-aware block swizzle: consecutive dispatch ids round-robin across the
// 8 XCDs; remapping wgid=(orig&7)*cpx+(orig>>3) gives each XCD a CONTIGUOUS
// chunk of row-panels, so its 4MB L2 holds 8 A-panels (2MB) instead of
// streaming the whole A matrix.  Bijective: nwg (1536 / 512) % 8 == 0.
// ---------------------------------------------------------------------------
template <bool OUT_F32>
__global__ __launch_bounds__(256)
void gemm_bt_kernel(const uint16_t* __restrict__ A, const uint16_t* __restrict__ Bt,
                    uint16_t* __restrict__ Cb, float* __restrict__ Cf,
                    int Mdim, int Ndim, int Kdim) {
    __shared__ uint16_t At[128 * 32];
    __shared__ uint16_t Bs[128 * 32];
    int tid = threadIdx.x;
    int wave = tid >> 6, lane = tid & 63, quad = lane >> 4, l15 = lane & 15;
    int nwgx = gridDim.x;
    int orig = blockIdx.y * nwgx + blockIdx.x;
    int cpx  = (nwgx * gridDim.y) >> 3;
    int wgid = (orig & 7) * cpx + (orig >> 3);
    int rowBase = (wgid / nwgx) * 128, colBase = (wgid % nwgx) * 128;
    int wRow = (wave >> 1) * 64, wCol = (wave & 1) * 64;
    int srow0 = tid >> 2, sseg0 = (tid & 3) * 8;
    int srow1 = (tid + 256) >> 2;
    f32x4 acc[4][4] = {};
    for (int kb = 0; kb < Kdim; kb += 32) {
        gld_lds16(&A [(size_t)(rowBase + srow0) * Kdim + kb + sseg0], &At[srow0 * 32 + sseg0]);
        gld_lds16(&A [(size_t)(rowBase + srow1) * Kdim + kb + sseg0], &At[srow1 * 32 + sseg0]);
        gld_lds16(&Bt[(size_t)(colBase + srow0) * Kdim + kb + sseg0], &Bs[srow0 * 32 + sseg0]);
        gld_lds16(&Bt[(size_t)(colBase + srow1) * Kdim + kb + sseg0], &Bs[srow1 * 32 + sseg0]);
        __syncthreads();
        bf16x8 af[4], bfr[4];
        #pragma unroll
        for (int m = 0; m < 4; m++) af[m]  = *(const bf16x8*)&At[(wRow + m * 16 + l15) * 32 + quad * 8];
        #pragma unroll
        for (int n = 0; n < 4; n++) bfr[n] = *(const bf16x8*)&Bs[(wCol + n * 16 + l15) * 32 + quad * 8];
        #pragma unroll
        for (int m = 0; m < 4; m++)
            #pragma unroll
            for (int n = 0; n < 4; n++)
                acc[m][n] = __builtin_amdgcn_mfma_f32_16x16x32_bf16(af[m], bfr[n], acc[m][n], 0, 0, 0);
        __syncthreads();
    }
    #pragma unroll
    for (int m = 0; m < 4; m++) {
        int row = rowBase + wRow + m * 16 + quad * 4;
        #pragma unroll
        for (int n = 0; n < 4; n++) {
            int col = colBase + wCol + n * 16 + l15;
            #pragma unroll
            for (int r = 0; r < 4; r++) {
                float v = acc[m][n][r];
                if (OUT_F32) Cf[(size_t)(row + r) * Ndim + col] = v;
                else         Cb[(size_t)(row + r) * Ndim + col] = f2b(v);
            }
        }
    }
}

// ---------------------------------------------------------------------------
// K4: RoPE on q,k; reshape (B,T,3D) -> (B,H,T,dh).
// Qr: linear (B,H,T,dh), PRE-SCALED by 1/sqrt(dh)*log2(e).
// Kr: SWIZZLED within each row: 16B chunk c of row t stored at chunk c^(t&7).
// __sincosf: hardware v_sin/v_cos path, one range reduction (th <= 2047 rad;
// trig error ~2e-4 << bf16 rounding).
// ---------------------------------------------------------------------------
__global__ void rope_kernel(const uint16_t* __restrict__ qkv,
                            uint16_t* __restrict__ Qr, uint16_t* __restrict__ Kr) {
    int g = blockIdx.x * 256 + threadIdx.x;
    int i  = g & 31;
    int t  = (g >> 5) & (T_ - 1);
    int bh = g >> 16;
    int h = bh & 15, b = bh >> 4;
    size_t rowoff = ((size_t)(b * T_ + t)) * 3072 + h * 64 + 2 * i;
    uint32_t qp = *(const uint32_t*)&qkv[rowoff];
    uint32_t kp = *(const uint32_t*)&qkv[rowoff + 1024];
    float qe = b2f((uint16_t)qp), qo = b2f((uint16_t)(qp >> 16));
    float ke = b2f((uint16_t)kp), ko = b2f((uint16_t)(kp >> 16));
    float inv = exp2f(-(float)i * (13.2877123795494f / 32.f));
    float th = (float)t * inv;
    float s, c;
    __sincosf(th, &s, &c);
    const float SC = 0.125f * 1.44269504089f;   // 1/sqrt(64) * log2(e), folded into Q
    uint32_t qw = (uint32_t)f2b((qe * c - qo * s) * SC)
                | ((uint32_t)f2b((qe * s + qo * c) * SC) << 16);
    uint32_t kw = (uint32_t)f2b(ke * c - ko * s) | ((uint32_t)f2b(ke * s + ko * c) << 16);
    size_t o = ((size_t)bh * T_ + t) * 64 + 2 * i;
    *(uint32_t*)&Qr[o] = qw;
    int d = 2 * i;
    size_t kidx = ((size_t)bh * T_ + t) * 64 + ((((d >> 3) ^ (t & 7)) << 3) | (d & 7));
    *(uint32_t*)&Kr[kidx] = kw;
}

// ---------------------------------------------------------------------------
// K5: V -> Vt via LDS tile transpose.  64-t tiles so a 64-kpos chunk is
// CONTIGUOUS 4096 elems in global (verbatim DMA in attn).  Within each
// (64 d x 64 t) tile, 16B t-chunk c of d-row stored at c^(d&7):
// vidx = bh*64*T + (t>>6)*4096 + d*64 + phys*8.
// ---------------------------------------------------------------------------
__global__ void vtrans_kernel(const uint16_t* __restrict__ qkv, uint16_t* __restrict__ Vt) {
    __shared__ uint16_t tile[32][72];
    int bh = blockIdx.y, t0 = blockIdx.x * 32;
    int b = bh >> 4, h = bh & 15;
    int tid = threadIdx.x;
    int r = tid >> 3, c8 = (tid & 7) * 8;
    *(u32x4*)&tile[r][c8] =
        *(const u32x4*)&qkv[((size_t)(b * T_ + t0 + r)) * 3072 + 2048 + h * 64 + c8];
    __syncthreads();
    int d = tid >> 2, t8 = (tid & 3) * 8;
    union { uint16_t s[8]; u32x4 v; } uu;
    #pragma unroll
    for (int j = 0; j < 8; j++) uu.s[j] = tile[t8 + j][d];
    int tt = t0 + t8;
    int c  = (tt & 63) >> 3;
    int phys = (c ^ (d & 7)) & 7;
    size_t vidx = (size_t)bh * 64 * T_ + (size_t)(tt >> 6) * 4096 + d * 64 + phys * 8;
    *(u32x4*)&Vt[vidx] = uu.v;
}

// ---------------------------------------------------------------------------
// K6: causal flash attention, S^T orientation, chunk=64 kpos.
// ROUND-4 VERIFIED STRUCTURE (81.2us) -- single-buffered verbatim DMA.
// Double-buffer prefetch (rounds 7/8) is retired: two implementations
// (compiler-drained and explicit vmcnt(0)-drained) both corrupted data
// while this single-buffer schedule passes; cause not identified at
// source level, so the schedule edit is off-limits per pre-commitment.
// LDS: K 8KB + V 8KB + P 9KB = 25.6KB -> 6 blocks/CU.  Grid 2048
// (one 64-row q-tile per block, heavy first) -> rich backfill (occ ~51%).
// ---------------------------------------------------------------------------
#define PSTR 72

__device__ __forceinline__ f32x4 mfma16(bf16x8 a, bf16x8 b, f32x4 c) {
    return __builtin_amdgcn_mfma_f32_16x16x32_bf16(a, b, c, 0, 0, 0);
}

template <bool MASKED>
__device__ __forceinline__ void attn_chunk_sw(
    const uint16_t* __restrict__ Kst, const uint16_t* __restrict__ Vst,
    uint16_t* __restrict__ Pw, int nact, int base_kmq,
    bf16x8 aQ0, bf16x8 aQ1, int l15, int quad,
    f32x4 (&Oacc)[4], float& mrow, float& lrow)
{
    int lx = l15 & 7;
    f32x4 sacc[4];
    if (MASKED) {                               // defined values on skipped tiles
        #pragma unroll
        for (int n = 0; n < 4; n++) sacc[n] = f32x4{0.f, 0.f, 0.f, 0.f};
    }
    #pragma unroll
    for (int n = 0; n < 4; n++) {
        if (MASKED && n >= nact) continue;
        int rowK = (n * 16 + l15) * 64;
        bf16x8 kv0 = *(const bf16x8*)&Kst[rowK + ((quad ^ lx) << 3)];
        bf16x8 kv1 = *(const bf16x8*)&Kst[rowK + (((quad + 4) ^ lx) << 3)];
        f32x4 s = {};
        s = mfma16(kv0, aQ0, s);
        s = mfma16(kv1, aQ1, s);
        sacc[n] = s;
    }
    // scores already scaled by 1/sqrt(dh)*log2e (folded into Q at rope time)
    float mx = -1e30f;
    #pragma unroll
    for (int n = 0; n < 4; n++) {
        if (MASKED && n >= nact) continue;
        if (MASKED) {
            #pragma unroll
            for (int r = 0; r < 4; r++) {
                int kmq = base_kmq + n * 16 + quad * 4 + r;   // kpos - q
                if (kmq > 0) sacc[n][r] = -1e30f;
            }
        }
        float t = max3f(sacc[n][0], sacc[n][1], sacc[n][2]);
        mx = max3f(mx, t, sacc[n][3]);
    }
    mx = fmaxf(mx, __shfl_xor(mx, 16, 64));
    mx = fmaxf(mx, __shfl_xor(mx, 32, 64));
    // defer-max: only rescale when the chunk max meaningfully exceeds the
    // running max (wave-uniform branch).  P values bounded by exp2(8)=256.
    if (!__all(mx <= mrow + 8.f)) {
        float mnew = fmaxf(mrow, mx);
        float alpha = exp2f(mrow - mnew);
        #pragma unroll
        for (int m = 0; m < 4; m++)
            #pragma unroll
            for (int r = 0; r < 4; r++) Oacc[m][r] *= alpha;
        lrow *= alpha;
        mrow = mnew;
    }
    float sum = 0.f;
    #pragma unroll
    for (int n = 0; n < 4; n++) {
        if (MASKED && n >= nact) continue;
        #pragma unroll
        for (int r = 0; r < 4; r++) {
            float e = exp2f(sacc[n][r] - mrow);
            sacc[n][r] = e;
            sum += e;
        }
    }
    sum += __shfl_xor(sum, 16, 64);
    sum += __shfl_xor(sum, 32, 64);
    lrow += sum;
    // P^T -> own LDS slab (wave-private, no barrier needed); packed converts
    #pragma unroll
    for (int n = 0; n < 4; n++) {
        if (MASKED && n >= nact) continue;
        uint2 pk;
        pk.x = cvtpk(sacc[n][0], sacc[n][1]);
        pk.y = cvtpk(sacc[n][2], sacc[n][3]);
        *(uint2*)&Pw[l15 * PSTR + n * 16 + quad * 4] = pk;
    }
    if (MASKED && (nact & 1)) {                 // zero odd tail tile for b128 reads
        uint2 z; z.x = 0u; z.y = 0u;
        *(uint2*)&Pw[l15 * PSTR + nact * 16 + quad * 4] = z;
    }
    int ssact = MASKED ? ((nact + 1) >> 1) : 2;
    #pragma unroll
    for (int ss = 0; ss < 2; ss++) {
        if (MASKED && ss >= ssact) continue;
        bf16x8 bP = *(const bf16x8*)&Pw[l15 * PSTR + ss * 32 + quad * 8];
        int cl = ss * 4 + quad;
        int phys = (cl ^ lx) & 7;
        #pragma unroll
        for (int m = 0; m < 4; m++) {
            bf16x8 aV = *(const bf16x8*)&Vst[(m * 16 + l15) * 64 + (phys << 3)];
            Oacc[m] = mfma16(aV, bP, Oacc[m]);
        }
    }
}

__global__ __launch_bounds__(256, 6)
void attn_kernel(const uint16_t* __restrict__ Qr, const uint16_t* __restrict__ Kr,
                 const uint16_t* __restrict__ Vt, uint16_t* __restrict__ Obuf) {
    __shared__ uint16_t KLDS[64 * 64];          // 8192 B, verbatim swizzled tile
    __shared__ uint16_t VLDS[64 * 64];          // 8192 B, verbatim swizzled tile
    __shared__ uint16_t Pl[4][16 * PSTR];       // 9216 B, wave-private slabs
    // XCD swizzle: 8 bh resident per XCD (K/V L2-local); heavy q-tiles first.
    int id  = blockIdx.x;
    int xcd = id & 7, grp = id >> 3;
    int bh  = xcd * 8 + (grp & 7);
    int qt  = 31 - (grp >> 3);                  // 31..0, heavy first
    int b = bh >> 4, h = bh & 15;
    int tid = threadIdx.x, wave = tid >> 6, lane = tid & 63, quad = lane >> 4, l15 = lane & 15;
    const uint16_t* Qbase = Qr + (size_t)bh * T_ * 64;
    const uint16_t* Kbase = Kr + (size_t)bh * T_ * 64;
    const uint16_t* Vbase = Vt + (size_t)bh * 64 * T_;
    uint16_t* Pw = &Pl[wave][0];
    int q0w = qt * 64 + wave * 16;
    bf16x8 aQ0 = *(const bf16x8*)&Qbase[(size_t)(q0w + l15) * 64 + quad * 8];
    bf16x8 aQ1 = *(const bf16x8*)&Qbase[(size_t)(q0w + l15) * 64 + 32 + quad * 8];
    f32x4 Oacc[4] = {};
    float mrow = -1e30f, lrow = 0.f;
    int nch = qt + 1;                           // 64-kpos chunks, uniform across waves
    int klim = q0w + 15;
    int idx0 = tid, idx1 = tid + 256;
    for (int c = 0; c < nch; c++) {
        int k0 = c * 64;
        __syncthreads();                        // (a) all waves done with prev K/V LDS
        const uint16_t* gK = Kbase + (size_t)k0 * 64;       // contiguous swizzled tile
        const uint16_t* gV = Vbase + (size_t)(k0 >> 6) * 4096;
        gld_lds16(gK + idx0 * 8, &KLDS[idx0 * 8]);
        gld_lds16(gK + idx1 * 8, &KLDS[idx1 * 8]);
        gld_lds16(gV + idx0 * 8, &VLDS[idx0 * 8]);
        gld_lds16(gV + idx1 * 8, &VLDS[idx1 * 8]);
        __syncthreads();                        // (b) DMA drained + visible
        if (c == nch - 1) {
            int nact = ((klim - k0) >> 4) + 1;  // causal tail: wave w -> w+1 tiles
            attn_chunk_sw<true>(KLDS, VLDS, Pw, nact, k0 - q0w - l15,
                                aQ0, aQ1, l15, quad, Oacc, mrow, lrow);
        } else {
            attn_chunk_sw<false>(KLDS, VLDS, Pw, 4, 0,
                                 aQ0, aQ1, l15, quad, Oacc, mrow, lrow);
        }
    }
    // epilogue: direct register -> global stores.  Lane (quad,l15) holds
    // O[q=q0w+l15][dh=m*16+quad*4+r]; 4 quads give 32B-contiguous segments.
    float invl = 1.0f / lrow;
    size_t obase = ((size_t)(b * T_ + q0w + l15)) * D_ + h * 64;
    #pragma unroll
    for (int m = 0; m < 4; m++) {
        uint2 ob;
        ob.x = cvtpk(Oacc[m][0] * invl, Oacc[m][1] * invl);
        ob.y = cvtpk(Oacc[m][2] * invl, Oacc[m][3] * invl);
        *(uint2*)&Obuf[obase + m * 16 + quad * 4] = ob;
    }
}

// ---------------------------------------------------------------------------
extern "C" void kernel_launch(void* const* d_in, const int* in_sizes, int n_in,
                              void* d_out, int out_size, void* d_ws, size_t ws_size,
                              hipStream_t stream) {
    const float* query = (const float*)d_in[0];
    const float* wq = (const float*)d_in[1];
    const float* wk = (const float*)d_in[2];
    const float* wv = (const float*)d_in[3];
    const float* wo = (const float*)d_in[4];
    const float* Aq = (const float*)d_in[5];
    const float* Bq = (const float*)d_in[6];
    const float* Av = (const float*)d_in[7];
    const float* Bv = (const float*)d_in[8];
    float* out = (float*)d_out;

    const size_t MB = 1ull << 20;
    if (ws_size < 120 * MB) return;
    char* ws = (char*)d_ws;
    uint16_t* Xbf = (uint16_t*)(ws);                   // 16 MB
    uint16_t* Wt  = (uint16_t*)(ws + 16 * MB);         //  8 MB
    uint16_t* qkv = (uint16_t*)(ws + 24 * MB);         // 48 MB
    uint16_t* Qr  = (uint16_t*)(ws + 72 * MB);         // 16 MB (pre-scaled)
    uint16_t* Kr  = (uint16_t*)(ws + 88 * MB);         // 16 MB (row-swizzled)
    uint16_t* Vt  = (uint16_t*)(ws + 104 * MB);        // 16 MB (64-t tile-swizzled)
    uint16_t* Obuf = qkv;                              // reuse (dead after rope/vtrans)

    cast_x_kernel<<<4096, 256, 0, stream>>>(query, Xbf);
    make_wt_kernel<<<dim3(16, 16, 4), 256, 0, stream>>>(wq, wk, wv, wo, Aq, Bq, Av, Bv, Wt);
    gemm_bt_kernel<false><<<dim3(3072 / 128, M_ / 128), 256, 0, stream>>>(
        Xbf, Wt, qkv, nullptr, M_, 3072, D_);
    rope_kernel<<<16384, 256, 0, stream>>>(qkv, Qr, Kr);
    vtrans_kernel<<<dim3(T_ / 32, B_ * H_), 256, 0, stream>>>(qkv, Vt);
    attn_kernel<<<2048, 256, 0, stream>>>(Qr, Kr, Vt, Obuf);
    gemm_bt_kernel<true><<<dim3(D_ / 128, M_ / 128), 256, 0, stream>>>(
        Obuf, Wt + 3ull * D_ * D_, nullptr, out, M_, D_, D_);
}